// Round 3
// baseline (260.643 us; speedup 1.0000x reference)
//
#include <hip/hip_runtime.h>
#include <hip/hip_bf16.h>
#include <stdint.h>

// Problem constants
#define B_ 32
#define N_ 4096
#define M_ 256
#define L_ 128
#define H_ 4
#define BN_ (B_ * N_)          // 131072 flattened rows

typedef __bf16 bf16x8 __attribute__((ext_vector_type(8)));
typedef float  f32x4  __attribute__((ext_vector_type(4)));
typedef float  f32x16 __attribute__((ext_vector_type(16)));

__device__ __forceinline__ unsigned short f2bf(float f) {
    // round-to-nearest-even f32 -> bf16
    unsigned int u = __float_as_uint(f);
    u += 0x7fffu + ((u >> 16) & 1u);
    return (unsigned short)(u >> 16);
}
__device__ __forceinline__ unsigned int pack2(float lo, float hi) {
    return (unsigned int)f2bf(lo) | ((unsigned int)f2bf(hi) << 16);
}

// async global->LDS, 16B per lane. LDS dest is wave-uniform base (+lane*16 by HW);
// global src is per-lane.
__device__ __forceinline__ void gload16(const void* g, void* l) {
    __builtin_amdgcn_global_load_lds(
        (const __attribute__((address_space(1))) unsigned int*)g,
        (__attribute__((address_space(3))) unsigned int*)l, 16, 0, 0);
}

// ---------------------------------------------------------------------------
// FAST PATH prep 1: x (BN,256) f32 -> xb: per (tile,ks) a 128x64 bf16 image,
// XOR-swizzled exactly as the GEMM's LDS wants it (byte ^= (row&7)<<4).
// FIX (round 2 bug): cover ALL 128 rows (4 reps of 32), not just rows 0-31.
// ---------------------------------------------------------------------------
__global__ void prep_x(const float* __restrict__ x, unsigned short* __restrict__ xb) {
    const int blk  = blockIdx.x;        // 4096 = 1024 tiles * 4 ks
    const int tile = blk >> 2, ks = blk & 3;
    const int i    = threadIdx.x;
    const int kk   = (i & 7) * 8;
    char* dst = (char*)xb + (size_t)blk * 16384;
#pragma unroll
    for (int rep = 0; rep < 4; ++rep) {
        int row = rep * 32 + (i >> 3);
        const float* gx = x + (size_t)(tile * 128 + row) * M_ + ks * 64 + kk;
        float4 a = *(const float4*)gx;
        float4 b = *(const float4*)(gx + 4);
        uint4 o;
        o.x = pack2(a.x, a.y); o.y = pack2(a.z, a.w);
        o.z = pack2(b.x, b.y); o.w = pack2(b.z, b.w);
        int byte = (row * 64 + kk) * 2;
        byte ^= (row & 7) << 4;
        *(uint4*)(dst + byte) = o;
    }
}

// ---------------------------------------------------------------------------
// FAST PATH prep 2: V,U (H,M,L) f32 -> vu images [(h*4+ks)*2+mat][128l x 64m]
// bf16, swizzled. Transpose via padded LDS slab (conflict-free).
// ---------------------------------------------------------------------------
__global__ void prep_vu_img(const float* __restrict__ V, const float* __restrict__ U,
                            unsigned short* __restrict__ vu) {
    __shared__ float slab[64][129];     // [m][l], padded
    const int b   = blockIdx.x;         // 32 = h(4) * ks(4) * mat(2)
    const int mat = b & 1, ks = (b >> 1) & 3, h = b >> 3;
    const float* src = (mat ? U : V) + ((size_t)h * M_ + ks * 64) * L_;
    const int tid = threadIdx.x;
#pragma unroll
    for (int rep = 0; rep < 32; ++rep) {
        int idx = rep * 256 + tid;      // 8192 = 64m x 128l
        slab[idx >> 7][idx & 127] = src[(size_t)(idx >> 7) * L_ + (idx & 127)];
    }
    __syncthreads();
    char* dst = (char*)vu + (size_t)b * 16384;
#pragma unroll
    for (int rep = 0; rep < 4; ++rep) {
        int cidx = rep * 256 + tid;     // 1024 chunks of 16B
        int l  = cidx >> 3;
        int kk = (cidx & 7) * 8;
        uint4 o;
        o.x = pack2(slab[kk + 0][l], slab[kk + 1][l]);
        o.y = pack2(slab[kk + 2][l], slab[kk + 3][l]);
        o.z = pack2(slab[kk + 4][l], slab[kk + 5][l]);
        o.w = pack2(slab[kk + 6][l], slab[kk + 7][l]);
        int byte = (l * 64 + kk) * 2;
        byte ^= (l & 7) << 4;
        *(uint4*)(dst + byte) = o;
    }
}

// ---------------------------------------------------------------------------
// FAST PATH GEMM: logits[b,h,n] = sum_l tanh(xV)*sigmoid(xU)*w[h,l]
// 32x32x16 MFMA. Block = 128 rows x (128 V-cols + 128 U-cols), one (tile,h).
// Wave w: rows (w&1)*64..+64, l in [(w>>1)*64, +64) for BOTH V and U
// -> gated pairing stays in-thread. acc = 2rf x 2cf x {V,U} x f32x16 = 128 VGPR.
// Staging = pure global_load_lds of pre-swizzled images (no VALU pack).
// Grid: h-inner + XCD swizzle -> 4 heads of a tile share L2.
// ---------------------------------------------------------------------------
__global__ __launch_bounds__(256, 2)
void gemm_fast(const unsigned short* __restrict__ xb,
               const unsigned short* __restrict__ vu,
               const float* __restrict__ w,
               float* __restrict__ logits) {
    __shared__ __align__(16) unsigned short xs[8192];  // 16KB image
    __shared__ __align__(16) unsigned short vs[8192];
    __shared__ __align__(16) unsigned short us[8192];
    __shared__ float wl[L_];
    __shared__ float part[2][128];

    const int orig    = blockIdx.x;                    // 4096, %8==0 -> bijective
    const int logical = (orig & 7) * 512 + (orig >> 3);
    const int tile    = logical >> 2;
    const int h       = logical & 3;

    const int tid  = threadIdx.x;
    const int lane = tid & 63;
    const int wv   = tid >> 6;
    const int cc   = lane & 31;
    const int hi   = lane >> 5;
    const int r0   = (wv & 1) * 64;        // wave's row base (local)
    const int L0   = (wv >> 1) * 64;       // wave's l base

    if (tid < L_) wl[tid] = w[h * L_ + tid];

    f32x16 accV[2][2], accU[2][2];
#pragma unroll
    for (int rf = 0; rf < 2; ++rf)
#pragma unroll
        for (int j = 0; j < 2; ++j) {
            accV[rf][j] = (f32x16)(0.f);
            accU[rf][j] = (f32x16)(0.f);
        }

    const char* xsrc0 = (const char*)xb + (size_t)tile * 4 * 16384;
    const char* vusrc = (const char*)vu + (size_t)h * 4 * 32768;

    for (int ks = 0; ks < 4; ++ks) {
        if (ks) __syncthreads();           // prior LDS reads done
        // ---- stage 48KB via global_load_lds (12 calls/wave) ----
        const char* xsrc = xsrc0 + ks * 16384;
        const char* vsrc = vusrc + ks * 32768;
        const char* usrc = vsrc + 16384;
#pragma unroll
        for (int j = 0; j < 4; ++j) {
            int off = (wv * 4 + j) * 1024;
            gload16(xsrc + off + lane * 16, (char*)xs + off);
            gload16(vsrc + off + lane * 16, (char*)vs + off);
            gload16(usrc + off + lane * 16, (char*)us + off);
        }
        __syncthreads();                   // drains vmcnt(0) + barrier

        // ---- MFMA: 4 ksubs x (2 rf x 2 V + 2 rf x 2 U) ----
#pragma unroll
        for (int ksub = 0; ksub < 4; ++ksub) {
            const int kb = ksub * 32 + hi * 16;   // byte col base
            bf16x8 a0, a1, bv0, bv1, bu0, bu1;
            {
                int r = r0 + cc;
                int byte = (r * 128 + kb) ^ ((r & 7) << 4);
                a0 = *(const bf16x8*)((const char*)xs + byte);
                r = r0 + 32 + cc;
                byte = (r * 128 + kb) ^ ((r & 7) << 4);
                a1 = *(const bf16x8*)((const char*)xs + byte);
                int l = L0 + cc;
                byte = (l * 128 + kb) ^ ((l & 7) << 4);
                bv0 = *(const bf16x8*)((const char*)vs + byte);
                bu0 = *(const bf16x8*)((const char*)us + byte);
                l = L0 + 32 + cc;
                byte = (l * 128 + kb) ^ ((l & 7) << 4);
                bv1 = *(const bf16x8*)((const char*)vs + byte);
                bu1 = *(const bf16x8*)((const char*)us + byte);
            }
            accV[0][0] = __builtin_amdgcn_mfma_f32_32x32x16_bf16(a0, bv0, accV[0][0], 0, 0, 0);
            accV[0][1] = __builtin_amdgcn_mfma_f32_32x32x16_bf16(a0, bv1, accV[0][1], 0, 0, 0);
            accU[0][0] = __builtin_amdgcn_mfma_f32_32x32x16_bf16(a0, bu0, accU[0][0], 0, 0, 0);
            accU[0][1] = __builtin_amdgcn_mfma_f32_32x32x16_bf16(a0, bu1, accU[0][1], 0, 0, 0);
            accV[1][0] = __builtin_amdgcn_mfma_f32_32x32x16_bf16(a1, bv0, accV[1][0], 0, 0, 0);
            accV[1][1] = __builtin_amdgcn_mfma_f32_32x32x16_bf16(a1, bv1, accV[1][1], 0, 0, 0);
            accU[1][0] = __builtin_amdgcn_mfma_f32_32x32x16_bf16(a1, bu0, accU[1][0], 0, 0, 0);
            accU[1][1] = __builtin_amdgcn_mfma_f32_32x32x16_bf16(a1, bu1, accU[1][1], 0, 0, 0);
        }
    }

    // ---- epilogue: gated = tanh(V)*sigmoid(U), dot w over l, reduce lanes ----
    const float w0 = wl[L0 + cc];
    const float w1 = wl[L0 + 32 + cc];
    float p[32];
#pragma unroll
    for (int rf = 0; rf < 2; ++rf)
#pragma unroll
        for (int i = 0; i < 16; ++i) {
            float s = 0.f;
#pragma unroll
            for (int j = 0; j < 2; ++j) {
                float vv = accV[rf][j][i];
                float uu = accU[rf][j][i];
                vv = fminf(fmaxf(vv, -20.f), 20.f);
                float A = __expf(2.f * vv);                 // tanh = (A-1)/(A+1)
                float E = __expf(fminf(-uu, 30.f));         // sigmoid = 1/(1+E)
                float g = __fdividef(A - 1.f, (A + 1.f) * (1.f + E));
                s += g * (j ? w1 : w0);
            }
            p[rf * 16 + i] = s;
        }

    // value-merging butterfly over the 32 low lanes: lane cc ends with the
    // full 64-l partial sum for slot bitrev5(cc).
#pragma unroll
    for (int st = 0; st < 5; ++st) {
        const int m = 1 << st;
        const int half = 16 >> st;
#pragma unroll
        for (int j = 0; j < half; ++j) {
            float send = (cc & m) ? p[j] : p[j + half];
            float recv = __shfl_xor(send, m, 64);
            float keep = (cc & m) ? p[j + half] : p[j];
            p[j] = keep + recv;
        }
    }
    {
        int slot = ((cc & 1) << 4) | ((cc & 2) << 2) | (cc & 4) | ((cc & 8) >> 2) | ((cc & 16) >> 4);
        int rf = slot >> 4, i = slot & 15;
        int rlocal = r0 + rf * 32 + (i & 3) + 8 * (i >> 2) + 4 * hi;
        part[wv >> 1][rlocal] = p[0];
    }
    __syncthreads();
    if (tid < 128) {
        float v = part[0][tid] + part[1][tid];
        int rowflat = tile * 128 + tid;
        int b = rowflat >> 12;
        int n = rowflat & (N_ - 1);
        logits[((size_t)b * H_ + h) * N_ + n] = v;
    }
}

// ---------------------------------------------------------------------------
// SLOW PATH (round-1 fallback, used only if ws_size is too small)
// ---------------------------------------------------------------------------
__global__ void prep_vu_slow(const float* __restrict__ V, const float* __restrict__ U,
                             unsigned short* __restrict__ Vt, unsigned short* __restrict__ Ut) {
    int idx = blockIdx.x * 256 + threadIdx.x;
    int m = idx & (M_ - 1);
    int l = (idx >> 8) & (L_ - 1);
    int h = idx >> 15;
    Vt[idx] = f2bf(V[((size_t)h * M_ + m) * L_ + l]);
    Ut[idx] = f2bf(U[((size_t)h * M_ + m) * L_ + l]);
}

#define BM 128
#define BK 64

__global__ __launch_bounds__(256, 2)
void gemm_logits(const float* __restrict__ x,
                 const unsigned short* __restrict__ Vt,
                 const unsigned short* __restrict__ Ut,
                 const float* __restrict__ w,
                 float* __restrict__ logits) {
    __shared__ __align__(16) unsigned short xs[BM * BK];
    __shared__ __align__(16) unsigned short vs[L_ * BK];
    __shared__ __align__(16) unsigned short us[L_ * BK];
    __shared__ float wl[L_];

    const int h    = blockIdx.x >> 10;
    const int tile = blockIdx.x & 1023;
    const int row0 = tile * BM;
    const int tid  = threadIdx.x;
    const int lane = tid & 63;
    const int wave = tid >> 6;

    if (tid < L_) wl[tid] = w[h * L_ + tid];

    f32x4 accV[2][8], accU[2][8];
#pragma unroll
    for (int rf = 0; rf < 2; ++rf)
#pragma unroll
        for (int cf = 0; cf < 8; ++cf) {
            accV[rf][cf] = (f32x4){0.f, 0.f, 0.f, 0.f};
            accU[rf][cf] = (f32x4){0.f, 0.f, 0.f, 0.f};
        }

    const unsigned short* Vh = Vt + (size_t)h * L_ * M_;
    const unsigned short* Uh = Ut + (size_t)h * L_ * M_;
    const int g = lane >> 4;
    const int c = lane & 15;

    for (int ks = 0; ks < 4; ++ks) {
        const int k0 = ks * BK;
        __syncthreads();
#pragma unroll
        for (int p = 0; p < 4; ++p) {
            int row = p * 32 + (tid >> 3);
            int kk  = (tid & 7) * 8;
            const float* gx = x + (size_t)(row0 + row) * M_ + k0 + kk;
            float4 a = *(const float4*)gx;
            float4 b = *(const float4*)(gx + 4);
            uint4 o;
            o.x = pack2(a.x, a.y); o.y = pack2(a.z, a.w);
            o.z = pack2(b.x, b.y); o.w = pack2(b.z, b.w);
            int byte = (row * BK + kk) * 2;
            byte ^= (row & 7) << 4;
            *(uint4*)((char*)xs + byte) = o;
        }
#pragma unroll
        for (int p = 0; p < 4; ++p) {
            int l  = p * 32 + (tid >> 3);
            int kk = (tid & 7) * 8;
            uint4 v = *(const uint4*)(Vh + (size_t)l * M_ + k0 + kk);
            uint4 u = *(const uint4*)(Uh + (size_t)l * M_ + k0 + kk);
            int byte = (l * BK + kk) * 2;
            byte ^= (l & 7) << 4;
            *(uint4*)((char*)vs + byte) = v;
            *(uint4*)((char*)us + byte) = u;
        }
        __syncthreads();
#pragma unroll
        for (int ksub = 0; ksub < 2; ++ksub) {
            bf16x8 afr[2];
#pragma unroll
            for (int rf = 0; rf < 2; ++rf) {
                int row = wave * 32 + rf * 16 + c;
                int byte = (row * BK + ksub * 32 + g * 8) * 2;
                byte ^= (row & 7) << 4;
                afr[rf] = *(const bf16x8*)((const char*)xs + byte);
            }
#pragma unroll
            for (int cf = 0; cf < 8; ++cf) {
                int l = cf * 16 + c;
                int byte = (l * BK + ksub * 32 + g * 8) * 2;
                byte ^= (l & 7) << 4;
                bf16x8 bv = *(const bf16x8*)((const char*)vs + byte);
                bf16x8 bu = *(const bf16x8*)((const char*)us + byte);
#pragma unroll
                for (int rf = 0; rf < 2; ++rf) {
                    accV[rf][cf] = __builtin_amdgcn_mfma_f32_16x16x32_bf16(afr[rf], bv, accV[rf][cf], 0, 0, 0);
                    accU[rf][cf] = __builtin_amdgcn_mfma_f32_16x16x32_bf16(afr[rf], bu, accU[rf][cf], 0, 0, 0);
                }
            }
        }
    }
#pragma unroll
    for (int rf = 0; rf < 2; ++rf) {
        float plog[4] = {0.f, 0.f, 0.f, 0.f};
#pragma unroll
        for (int cf = 0; cf < 8; ++cf) {
            float wvv = wl[cf * 16 + c];
#pragma unroll
            for (int i = 0; i < 4; ++i) {
                float vv = accV[rf][cf][i];
                float uu = accU[rf][cf][i];
                vv = fminf(fmaxf(vv, -20.f), 20.f);
                float e2v = __expf(2.f * vv);
                float t = __fdividef(e2v - 1.f, e2v + 1.f);
                float s = __fdividef(1.f, 1.f + __expf(-uu));
                plog[i] += t * s * wvv;
            }
        }
#pragma unroll
        for (int i = 0; i < 4; ++i) {
            float v = plog[i];
            v += __shfl_xor(v, 1);
            v += __shfl_xor(v, 2);
            v += __shfl_xor(v, 4);
            v += __shfl_xor(v, 8);
            if (c == 0) {
                int rowflat = row0 + wave * 32 + rf * 16 + g * 4 + i;
                int b = rowflat >> 12;
                int n = rowflat & (N_ - 1);
                logits[((size_t)b * H_ + h) * N_ + n] = v;
            }
        }
    }
}

// ---------------------------------------------------------------------------
// softmax^2 (first normalization cancels): a = e^2/sum(e^2), e = m*exp(m*l).
// ---------------------------------------------------------------------------
__global__ __launch_bounds__(256)
void softmax_att(const float* __restrict__ logits, const float* __restrict__ masks,
                 float* __restrict__ att) {
    const int bh = blockIdx.x;
    const int b = bh >> 2, h = bh & 3;
    __shared__ float e2s[N_];
    __shared__ float red[4];
    const int tid = threadIdx.x;

    float sum = 0.f;
#pragma unroll
    for (int i = 0; i < N_ / 256; ++i) {
        int n = i * 256 + tid;
        float lg = logits[((size_t)b * H_ + h) * N_ + n];
        float mv = masks[(size_t)b * N_ + n];
        float e = mv * __expf(mv * lg);
        float e2 = e * e;
        e2s[n] = e2;
        sum += e2;
    }
#pragma unroll
    for (int off = 32; off >= 1; off >>= 1) sum += __shfl_xor(sum, off);
    if ((tid & 63) == 0) red[tid >> 6] = sum;
    __syncthreads();
    float S = red[0] + red[1] + red[2] + red[3];
    float inv = 1.f / S;
#pragma unroll
    for (int i = 0; i < N_ / 256; ++i) {
        int n = i * 256 + tid;
        att[((size_t)h * B_ + b) * N_ + n] = e2s[n] * inv;
    }
}

// ---------------------------------------------------------------------------
// emb: 2-stage deterministic reduction.
// ---------------------------------------------------------------------------
#define NCH 32
#define CHUNK (N_ / NCH)   // 128

__global__ __launch_bounds__(256)
void emb_partial(const float* __restrict__ x, const float* __restrict__ att,
                 float* __restrict__ part) {
    const int bc = blockIdx.x;
    const int b = bc >> 5, ch = bc & 31;
    __shared__ float as[H_][CHUNK];
    const int tid = threadIdx.x;

    for (int i = tid; i < H_ * CHUNK; i += 256) {
        int hh = i >> 7;
        int j  = i & (CHUNK - 1);
        as[hh][j] = att[((size_t)hh * B_ + b) * N_ + ch * CHUNK + j];
    }
    __syncthreads();

    float a0 = 0.f, a1 = 0.f, a2 = 0.f, a3 = 0.f;
    const float* xp = x + ((size_t)b * N_ + ch * CHUNK) * M_ + tid;
#pragma unroll 4
    for (int j = 0; j < CHUNK; ++j) {
        float xv = xp[(size_t)j * M_];
        a0 += as[0][j] * xv;
        a1 += as[1][j] * xv;
        a2 += as[2][j] * xv;
        a3 += as[3][j] * xv;
    }
    float* pp = part + (size_t)bc * H_ * M_ + tid;
    pp[0 * M_] = a0; pp[1 * M_] = a1; pp[2 * M_] = a2; pp[3 * M_] = a3;
}

__global__ __launch_bounds__(256)
void emb_reduce(const float* __restrict__ part, float* __restrict__ emb) {
    int idx = blockIdx.x * 256 + threadIdx.x;
    int b = idx >> 10;
    int r = idx & 1023;
    float s = 0.f;
#pragma unroll
    for (int ci = 0; ci < NCH; ++ci)
        s += part[((size_t)(b * NCH + ci)) * (H_ * M_) + r];
    emb[idx] = s;
}

// ---------------------------------------------------------------------------
extern "C" void kernel_launch(void* const* d_in, const int* in_sizes, int n_in,
                              void* d_out, int out_size, void* d_ws, size_t ws_size,
                              hipStream_t stream) {
    const float* x     = (const float*)d_in[0];
    const float* masks = (const float*)d_in[1];
    const float* V     = (const float*)d_in[2];
    const float* U     = (const float*)d_in[3];
    const float* w     = (const float*)d_in[4];

    float* att = (float*)d_out;                       // (H,B,N,1)
    float* emb = att + (size_t)H_ * B_ * N_;          // (B,H*M)

    char* ws = (char*)d_ws;
    const size_t XB_BYTES  = (size_t)1024 * 4 * 16384;        // 67,108,864
    const size_t VU_BYTES  = (size_t)32 * 16384;              // 524,288
    const size_t LG_BYTES  = (size_t)B_ * H_ * N_ * 4;        // 2,097,152
    const size_t PT_BYTES  = (size_t)B_ * NCH * H_ * M_ * 4;  // 4,194,304
    const size_t NEED_FAST = XB_BYTES + VU_BYTES + LG_BYTES + PT_BYTES;

    float* logits;
    float* partp;

    if (ws_size >= NEED_FAST) {
        unsigned short* xb = (unsigned short*)ws;
        unsigned short* vu = (unsigned short*)(ws + XB_BYTES);
        logits = (float*)(ws + XB_BYTES + VU_BYTES);
        partp  = (float*)(ws + XB_BYTES + VU_BYTES + LG_BYTES);

        prep_x    <<<4096, 256, 0, stream>>>(x, xb);
        prep_vu_img<<<32,  256, 0, stream>>>(V, U, vu);
        gemm_fast <<<4096, 256, 0, stream>>>(xb, vu, w, logits);
    } else {
        unsigned short* Vt = (unsigned short*)ws;
        unsigned short* Ut = (unsigned short*)(ws + 262144);
        logits = (float*)(ws + 524288);
        partp  = (float*)(ws + 524288 + LG_BYTES);

        prep_vu_slow<<<512, 256, 0, stream>>>(V, U, Vt, Ut);
        gemm_logits <<<4096, 256, 0, stream>>>(x, Vt, Ut, w, logits);
    }

    softmax_att<<<B_ * H_,              256, 0, stream>>>(logits, masks, att);
    emb_partial<<<B_ * NCH,             256, 0, stream>>>(x, att, partp);
    emb_reduce <<<(B_ * H_ * M_) / 256, 256, 0, stream>>>(partp, emb);
}

// Round 4
// 185.154 us; speedup vs baseline: 1.4077x; 1.4077x over previous
//
#include <hip/hip_runtime.h>
#include <hip/hip_bf16.h>
#include <stdint.h>

// Problem constants
#define B_ 32
#define N_ 4096
#define M_ 256
#define L_ 128
#define H_ 4
#define BN_ (B_ * N_)          // 131072 flattened rows

typedef __bf16 bf16x8 __attribute__((ext_vector_type(8)));
typedef float  f32x4  __attribute__((ext_vector_type(4)));

__device__ __forceinline__ unsigned short f2bf(float f) {
    // round-to-nearest-even f32 -> bf16
    unsigned int u = __float_as_uint(f);
    u += 0x7fffu + ((u >> 16) & 1u);
    return (unsigned short)(u >> 16);
}
__device__ __forceinline__ unsigned int pack2(float lo, float hi) {
    return (unsigned int)f2bf(lo) | ((unsigned int)f2bf(hi) << 16);
}

// async global->LDS, 16B per lane. LDS dest is wave-uniform base (+lane*16 by HW);
// global src is per-lane.
__device__ __forceinline__ void gload16(const void* g, void* l) {
    __builtin_amdgcn_global_load_lds(
        (const __attribute__((address_space(1))) unsigned int*)g,
        (__attribute__((address_space(3))) unsigned int*)l, 16, 0, 0);
}

// Image geometry: each K-step image is [128 rows][32 k] bf16 = 8192 B,
// row stride 64 B, swizzle byte ^= (row&6)<<3  (row bits 1-2 -> byte bits 4-5).
// 16-lane fragment groups read 16 distinct rows at fixed 16B col -> 8 slots
// x 2 lanes = 2-way (free), the round-1 proven-zero-conflict pattern.

// ---------------------------------------------------------------------------
// prep 1: x (BN,256) f32 -> xb images: tile t in [0,1024), step s in [0,8):
// image base = (tile*8 + s)*8192.
// ---------------------------------------------------------------------------
__global__ void prep_x(const float* __restrict__ x, unsigned short* __restrict__ xb) {
    const int blk  = blockIdx.x;        // 4096 = 1024 tiles * 4 ks64
    const int tile = blk >> 2, ks = blk & 3;
    const int i    = threadIdx.x;
    const int kk   = (i & 7) * 8;       // 0..56 within the 64-col chunk
    const int tl   = kk >> 5;           // which 32-k image half
    const int kl   = kk & 31;
    char* dst = (char*)xb + ((size_t)tile * 8 + ks * 2 + tl) * 8192;
#pragma unroll
    for (int rep = 0; rep < 4; ++rep) {
        int row = rep * 32 + (i >> 3);
        const float* gx = x + (size_t)(tile * 128 + row) * M_ + ks * 64 + kk;
        float4 a = *(const float4*)gx;
        float4 b = *(const float4*)(gx + 4);
        uint4 o;
        o.x = pack2(a.x, a.y); o.y = pack2(a.z, a.w);
        o.z = pack2(b.x, b.y); o.w = pack2(b.z, b.w);
        int byte = (row * 64 + kl * 2) ^ ((row & 6) << 3);
        *(uint4*)(dst + byte) = o;
    }
}

// ---------------------------------------------------------------------------
// prep 2: V,U (H,M,L) f32 -> vu images [(h*8 + s)*2 + mat][128 l][32 m] bf16,
// swizzled. Transpose via padded LDS slab (conflict-free).
// ---------------------------------------------------------------------------
__global__ void prep_vu_img(const float* __restrict__ V, const float* __restrict__ U,
                            unsigned short* __restrict__ vu) {
    __shared__ float slab[64][129];     // [m][l], padded
    const int b   = blockIdx.x;         // 32 = h(4) * ks64(4) * mat(2)
    const int mat = b & 1, ks = (b >> 1) & 3, h = b >> 3;
    const float* src = (mat ? U : V) + ((size_t)h * M_ + ks * 64) * L_;
    const int tid = threadIdx.x;
#pragma unroll
    for (int rep = 0; rep < 32; ++rep) {
        int idx = rep * 256 + tid;      // 8192 = 64m x 128l
        slab[idx >> 7][idx & 127] = src[(size_t)(idx >> 7) * L_ + (idx & 127)];
    }
    __syncthreads();
#pragma unroll
    for (int rep = 0; rep < 4; ++rep) {
        int cidx = rep * 256 + tid;     // 1024 chunks of 16B (two 8KB images)
        int l  = cidx >> 3;             // 0..127
        int kk = (cidx & 7) * 8;        // 0..56
        uint4 o;
        o.x = pack2(slab[kk + 0][l], slab[kk + 1][l]);
        o.y = pack2(slab[kk + 2][l], slab[kk + 3][l]);
        o.z = pack2(slab[kk + 4][l], slab[kk + 5][l]);
        o.w = pack2(slab[kk + 6][l], slab[kk + 7][l]);
        int tl = kk >> 5, kl = kk & 31;
        char* dst = (char*)vu + (((size_t)(h * 8 + ks * 2 + tl)) * 2 + mat) * 8192;
        int byte = (l * 64 + kl * 2) ^ ((l & 6) << 3);
        *(uint4*)(dst + byte) = o;
    }
}

// ---------------------------------------------------------------------------
// Pipelined fused GEMM: logits[b,h,n] = sum_l tanh(xV)*sigmoid(xU)*w[h,l]
// 16x16x32 MFMA; block = 128 rows x 128 l x {V,U}, one (tile,h); 4 waves,
// wave wv owns rows wv*32..+32 and all 128 l. BK=32, 8 K-steps,
// double-buffered LDS (3x 2x8KB = 48KB -> 3 blocks/CU). Stage t+1 issued
// BEFORE compute(t); the trailing __syncthreads (vmcnt0 drain + barrier)
// lets stage loads land under MFMA (T3-minimum pipeline).
// Grid: h-inner + bijective XCD swizzle -> 4 heads of a tile share L2.
// ---------------------------------------------------------------------------
__global__ __launch_bounds__(256, 3)
void gemm_fast2(const unsigned short* __restrict__ xb,
                const unsigned short* __restrict__ vu,
                const float* __restrict__ w,
                float* __restrict__ logits) {
    __shared__ __align__(16) unsigned short xs[2][4096];   // 2 x 8KB
    __shared__ __align__(16) unsigned short vs[2][4096];
    __shared__ __align__(16) unsigned short us[2][4096];
    __shared__ float wl[L_];

    const int orig    = blockIdx.x;                 // 4096, %8==0 -> bijective
    const int logical = (orig & 7) * 512 + (orig >> 3);
    const int tile    = logical >> 2;
    const int h       = logical & 3;

    const int tid  = threadIdx.x;
    const int lane = tid & 63;
    const int wv   = tid >> 6;
    const int g    = lane >> 4;     // k-group 0..3 (k = g*8 + j)
    const int c    = lane & 15;     // row (A) / col (B) within fragment

    if (tid < L_) wl[tid] = w[h * L_ + tid];

    f32x4 accV[2][8], accU[2][8];
#pragma unroll
    for (int rf = 0; rf < 2; ++rf)
#pragma unroll
        for (int cf = 0; cf < 8; ++cf) {
            accV[rf][cf] = (f32x4){0.f, 0.f, 0.f, 0.f};
            accU[rf][cf] = (f32x4){0.f, 0.f, 0.f, 0.f};
        }

    const char* xim = (const char*)xb + (size_t)tile * 65536;   // 8 images
    const char* vim = (const char*)vu + (size_t)h * 131072;     // 8 x {v,u}
    const int soff = wv * 2048;     // this wave's quarter of each 8KB image

    // prologue: stage step 0 into buf 0 (6 gload16 per wave)
    {
        const char* vsrc = vim;
        const char* usrc = vim + 8192;
        gload16(xim  + soff +        lane * 16, (char*)xs[0] + soff);
        gload16(xim  + soff + 1024 + lane * 16, (char*)xs[0] + soff + 1024);
        gload16(vsrc + soff +        lane * 16, (char*)vs[0] + soff);
        gload16(vsrc + soff + 1024 + lane * 16, (char*)vs[0] + soff + 1024);
        gload16(usrc + soff +        lane * 16, (char*)us[0] + soff);
        gload16(usrc + soff + 1024 + lane * 16, (char*)us[0] + soff + 1024);
    }
    __syncthreads();

    for (int t = 0; t < 8; ++t) {
        const int buf = t & 1;
        if (t < 7) {                 // issue next-step stage BEFORE compute
            const char* xsrc = xim + (t + 1) * 8192;
            const char* vsrc = vim + (t + 1) * 16384;
            const char* usrc = vsrc + 8192;
            gload16(xsrc + soff +        lane * 16, (char*)xs[buf ^ 1] + soff);
            gload16(xsrc + soff + 1024 + lane * 16, (char*)xs[buf ^ 1] + soff + 1024);
            gload16(vsrc + soff +        lane * 16, (char*)vs[buf ^ 1] + soff);
            gload16(vsrc + soff + 1024 + lane * 16, (char*)vs[buf ^ 1] + soff + 1024);
            gload16(usrc + soff +        lane * 16, (char*)us[buf ^ 1] + soff);
            gload16(usrc + soff + 1024 + lane * 16, (char*)us[buf ^ 1] + soff + 1024);
        }
        // ---- compute on buf: 2 A-frags, 8 colfrags x {V,U} = 32 MFMA ----
        bf16x8 a0, a1;
        {
            int r = wv * 32 + c;
            int byte = (r * 64 + g * 16) ^ ((r & 6) << 3);
            a0 = *(const bf16x8*)((const char*)xs[buf] + byte);
            r += 16;
            byte = (r * 64 + g * 16) ^ ((r & 6) << 3);
            a1 = *(const bf16x8*)((const char*)xs[buf] + byte);
        }
#pragma unroll
        for (int cf = 0; cf < 8; ++cf) {
            int l = cf * 16 + c;
            int byte = (l * 64 + g * 16) ^ ((l & 6) << 3);
            bf16x8 bv = *(const bf16x8*)((const char*)vs[buf] + byte);
            bf16x8 bu = *(const bf16x8*)((const char*)us[buf] + byte);
            accV[0][cf] = __builtin_amdgcn_mfma_f32_16x16x32_bf16(a0, bv, accV[0][cf], 0, 0, 0);
            accV[1][cf] = __builtin_amdgcn_mfma_f32_16x16x32_bf16(a1, bv, accV[1][cf], 0, 0, 0);
            accU[0][cf] = __builtin_amdgcn_mfma_f32_16x16x32_bf16(a0, bu, accU[0][cf], 0, 0, 0);
            accU[1][cf] = __builtin_amdgcn_mfma_f32_16x16x32_bf16(a1, bu, accU[1][cf], 0, 0, 0);
        }
        __syncthreads();             // drains next-stage vmcnt(0) + barrier
    }

    // ---- epilogue: gated = tanh(V)*sigmoid(U), dot w over l, 16-lane reduce ----
#pragma unroll
    for (int rf = 0; rf < 2; ++rf) {
        float plog[4] = {0.f, 0.f, 0.f, 0.f};
#pragma unroll
        for (int cf = 0; cf < 8; ++cf) {
            float wvv = wl[cf * 16 + c];
#pragma unroll
            for (int i = 0; i < 4; ++i) {
                float vv = accV[rf][cf][i];
                float uu = accU[rf][cf][i];
                vv = fminf(fmaxf(vv, -20.f), 20.f);
                float A = __expf(2.f * vv);                 // tanh = (A-1)/(A+1)
                float E = __expf(fminf(-uu, 30.f));         // sigmoid = 1/(1+E)
                float gg = __fdividef(A - 1.f, (A + 1.f) * (1.f + E));
                plog[i] += gg * wvv;
            }
        }
#pragma unroll
        for (int i = 0; i < 4; ++i) {
            float v = plog[i];
            v += __shfl_xor(v, 1);
            v += __shfl_xor(v, 2);
            v += __shfl_xor(v, 4);
            v += __shfl_xor(v, 8);      // sum over the 16 col-lanes
            if (c == 0) {
                int rowflat = tile * 128 + wv * 32 + rf * 16 + g * 4 + i;
                int b = rowflat >> 12;           // / N_
                int n = rowflat & (N_ - 1);
                logits[((size_t)b * H_ + h) * N_ + n] = v;
            }
        }
    }
}

// ---------------------------------------------------------------------------
// SLOW PATH (round-1 fallback, used only if ws_size is too small)
// ---------------------------------------------------------------------------
__global__ void prep_vu_slow(const float* __restrict__ V, const float* __restrict__ U,
                             unsigned short* __restrict__ Vt, unsigned short* __restrict__ Ut) {
    int idx = blockIdx.x * 256 + threadIdx.x;
    int m = idx & (M_ - 1);
    int l = (idx >> 8) & (L_ - 1);
    int h = idx >> 15;
    Vt[idx] = f2bf(V[((size_t)h * M_ + m) * L_ + l]);
    Ut[idx] = f2bf(U[((size_t)h * M_ + m) * L_ + l]);
}

#define BM 128
#define BK 64

__global__ __launch_bounds__(256, 2)
void gemm_logits(const float* __restrict__ x,
                 const unsigned short* __restrict__ Vt,
                 const unsigned short* __restrict__ Ut,
                 const float* __restrict__ w,
                 float* __restrict__ logits) {
    __shared__ __align__(16) unsigned short xs[BM * BK];
    __shared__ __align__(16) unsigned short vs[L_ * BK];
    __shared__ __align__(16) unsigned short us[L_ * BK];
    __shared__ float wl[L_];

    const int h    = blockIdx.x >> 10;
    const int tile = blockIdx.x & 1023;
    const int row0 = tile * BM;
    const int tid  = threadIdx.x;
    const int lane = tid & 63;
    const int wave = tid >> 6;

    if (tid < L_) wl[tid] = w[h * L_ + tid];

    f32x4 accV[2][8], accU[2][8];
#pragma unroll
    for (int rf = 0; rf < 2; ++rf)
#pragma unroll
        for (int cf = 0; cf < 8; ++cf) {
            accV[rf][cf] = (f32x4){0.f, 0.f, 0.f, 0.f};
            accU[rf][cf] = (f32x4){0.f, 0.f, 0.f, 0.f};
        }

    const unsigned short* Vh = Vt + (size_t)h * L_ * M_;
    const unsigned short* Uh = Ut + (size_t)h * L_ * M_;
    const int g = lane >> 4;
    const int c = lane & 15;

    for (int ks = 0; ks < 4; ++ks) {
        const int k0 = ks * BK;
        __syncthreads();
#pragma unroll
        for (int p = 0; p < 4; ++p) {
            int row = p * 32 + (tid >> 3);
            int kk  = (tid & 7) * 8;
            const float* gx = x + (size_t)(row0 + row) * M_ + k0 + kk;
            float4 a = *(const float4*)gx;
            float4 b = *(const float4*)(gx + 4);
            uint4 o;
            o.x = pack2(a.x, a.y); o.y = pack2(a.z, a.w);
            o.z = pack2(b.x, b.y); o.w = pack2(b.z, b.w);
            int byte = (row * BK + kk) * 2;
            byte ^= (row & 7) << 4;
            *(uint4*)((char*)xs + byte) = o;
        }
#pragma unroll
        for (int p = 0; p < 4; ++p) {
            int l  = p * 32 + (tid >> 3);
            int kk = (tid & 7) * 8;
            uint4 v = *(const uint4*)(Vh + (size_t)l * M_ + k0 + kk);
            uint4 u = *(const uint4*)(Uh + (size_t)l * M_ + k0 + kk);
            int byte = (l * BK + kk) * 2;
            byte ^= (l & 7) << 4;
            *(uint4*)((char*)vs + byte) = v;
            *(uint4*)((char*)us + byte) = u;
        }
        __syncthreads();
#pragma unroll
        for (int ksub = 0; ksub < 2; ++ksub) {
            bf16x8 afr[2];
#pragma unroll
            for (int rf = 0; rf < 2; ++rf) {
                int row = wave * 32 + rf * 16 + c;
                int byte = (row * BK + ksub * 32 + g * 8) * 2;
                byte ^= (row & 7) << 4;
                afr[rf] = *(const bf16x8*)((const char*)xs + byte);
            }
#pragma unroll
            for (int cf = 0; cf < 8; ++cf) {
                int l = cf * 16 + c;
                int byte = (l * BK + ksub * 32 + g * 8) * 2;
                byte ^= (l & 7) << 4;
                bf16x8 bv = *(const bf16x8*)((const char*)vs + byte);
                bf16x8 bu = *(const bf16x8*)((const char*)us + byte);
#pragma unroll
                for (int rf = 0; rf < 2; ++rf) {
                    accV[rf][cf] = __builtin_amdgcn_mfma_f32_16x16x32_bf16(afr[rf], bv, accV[rf][cf], 0, 0, 0);
                    accU[rf][cf] = __builtin_amdgcn_mfma_f32_16x16x32_bf16(afr[rf], bu, accU[rf][cf], 0, 0, 0);
                }
            }
        }
    }
#pragma unroll
    for (int rf = 0; rf < 2; ++rf) {
        float plog[4] = {0.f, 0.f, 0.f, 0.f};
#pragma unroll
        for (int cf = 0; cf < 8; ++cf) {
            float wvv = wl[cf * 16 + c];
#pragma unroll
            for (int i = 0; i < 4; ++i) {
                float vv = accV[rf][cf][i];
                float uu = accU[rf][cf][i];
                vv = fminf(fmaxf(vv, -20.f), 20.f);
                float e2v = __expf(2.f * vv);
                float t = __fdividef(e2v - 1.f, e2v + 1.f);
                float s = __fdividef(1.f, 1.f + __expf(-uu));
                plog[i] += t * s * wvv;
            }
        }
#pragma unroll
        for (int i = 0; i < 4; ++i) {
            float v = plog[i];
            v += __shfl_xor(v, 1);
            v += __shfl_xor(v, 2);
            v += __shfl_xor(v, 4);
            v += __shfl_xor(v, 8);
            if (c == 0) {
                int rowflat = row0 + wave * 32 + rf * 16 + g * 4 + i;
                int b = rowflat >> 12;
                int n = rowflat & (N_ - 1);
                logits[((size_t)b * H_ + h) * N_ + n] = v;
            }
        }
    }
}

// ---------------------------------------------------------------------------
// softmax^2 (first normalization cancels): a = e^2/sum(e^2), e = m*exp(m*l).
// ---------------------------------------------------------------------------
__global__ __launch_bounds__(256)
void softmax_att(const float* __restrict__ logits, const float* __restrict__ masks,
                 float* __restrict__ att) {
    const int bh = blockIdx.x;
    const int b = bh >> 2, h = bh & 3;
    __shared__ float e2s[N_];
    __shared__ float red[4];
    const int tid = threadIdx.x;

    float sum = 0.f;
#pragma unroll
    for (int i = 0; i < N_ / 256; ++i) {
        int n = i * 256 + tid;
        float lg = logits[((size_t)b * H_ + h) * N_ + n];
        float mv = masks[(size_t)b * N_ + n];
        float e = mv * __expf(mv * lg);
        float e2 = e * e;
        e2s[n] = e2;
        sum += e2;
    }
#pragma unroll
    for (int off = 32; off >= 1; off >>= 1) sum += __shfl_xor(sum, off);
    if ((tid & 63) == 0) red[tid >> 6] = sum;
    __syncthreads();
    float S = red[0] + red[1] + red[2] + red[3];
    float inv = 1.f / S;
#pragma unroll
    for (int i = 0; i < N_ / 256; ++i) {
        int n = i * 256 + tid;
        att[((size_t)h * B_ + b) * N_ + n] = e2s[n] * inv;
    }
}

// ---------------------------------------------------------------------------
// emb: 2-stage deterministic reduction.
// ---------------------------------------------------------------------------
#define NCH 32
#define CHUNK (N_ / NCH)   // 128

__global__ __launch_bounds__(256)
void emb_partial(const float* __restrict__ x, const float* __restrict__ att,
                 float* __restrict__ part) {
    const int bc = blockIdx.x;
    const int b = bc >> 5, ch = bc & 31;
    __shared__ float as[H_][CHUNK];
    const int tid = threadIdx.x;

    for (int i = tid; i < H_ * CHUNK; i += 256) {
        int hh = i >> 7;
        int j  = i & (CHUNK - 1);
        as[hh][j] = att[((size_t)hh * B_ + b) * N_ + ch * CHUNK + j];
    }
    __syncthreads();

    float a0 = 0.f, a1 = 0.f, a2 = 0.f, a3 = 0.f;
    const float* xp = x + ((size_t)b * N_ + ch * CHUNK) * M_ + tid;
#pragma unroll 4
    for (int j = 0; j < CHUNK; ++j) {
        float xv = xp[(size_t)j * M_];
        a0 += as[0][j] * xv;
        a1 += as[1][j] * xv;
        a2 += as[2][j] * xv;
        a3 += as[3][j] * xv;
    }
    float* pp = part + (size_t)bc * H_ * M_ + tid;
    pp[0 * M_] = a0; pp[1 * M_] = a1; pp[2 * M_] = a2; pp[3 * M_] = a3;
}

__global__ __launch_bounds__(256)
void emb_reduce(const float* __restrict__ part, float* __restrict__ emb) {
    int idx = blockIdx.x * 256 + threadIdx.x;
    int b = idx >> 10;
    int r = idx & 1023;
    float s = 0.f;
#pragma unroll
    for (int ci = 0; ci < NCH; ++ci)
        s += part[((size_t)(b * NCH + ci)) * (H_ * M_) + r];
    emb[idx] = s;
}

// ---------------------------------------------------------------------------
extern "C" void kernel_launch(void* const* d_in, const int* in_sizes, int n_in,
                              void* d_out, int out_size, void* d_ws, size_t ws_size,
                              hipStream_t stream) {
    const float* x     = (const float*)d_in[0];
    const float* masks = (const float*)d_in[1];
    const float* V     = (const float*)d_in[2];
    const float* U     = (const float*)d_in[3];
    const float* w     = (const float*)d_in[4];

    float* att = (float*)d_out;                       // (H,B,N,1)
    float* emb = att + (size_t)H_ * B_ * N_;          // (B,H*M)

    char* ws = (char*)d_ws;
    const size_t XB_BYTES  = (size_t)1024 * 8 * 8192;         // 67,108,864
    const size_t VU_BYTES  = (size_t)64 * 8192;               // 524,288
    const size_t LG_BYTES  = (size_t)B_ * H_ * N_ * 4;        // 2,097,152
    const size_t PT_BYTES  = (size_t)B_ * NCH * H_ * M_ * 4;  // 4,194,304
    const size_t NEED_FAST = XB_BYTES + VU_BYTES + LG_BYTES + PT_BYTES;

    float* logits;
    float* partp;

    if (ws_size >= NEED_FAST) {
        unsigned short* xb = (unsigned short*)ws;
        unsigned short* vu = (unsigned short*)(ws + XB_BYTES);
        logits = (float*)(ws + XB_BYTES + VU_BYTES);
        partp  = (float*)(ws + XB_BYTES + VU_BYTES + LG_BYTES);

        prep_x     <<<4096, 256, 0, stream>>>(x, xb);
        prep_vu_img<<<32,   256, 0, stream>>>(V, U, vu);
        gemm_fast2 <<<4096, 256, 0, stream>>>(xb, vu, w, logits);
    } else {
        unsigned short* Vt = (unsigned short*)ws;
        unsigned short* Ut = (unsigned short*)(ws + 262144);
        logits = (float*)(ws + 524288);
        partp  = (float*)(ws + 524288 + LG_BYTES);

        prep_vu_slow<<<512, 256, 0, stream>>>(V, U, Vt, Ut);
        gemm_logits <<<4096, 256, 0, stream>>>(x, Vt, Ut, w, logits);
    }

    softmax_att<<<B_ * H_,              256, 0, stream>>>(logits, masks, att);
    emb_partial<<<B_ * NCH,             256, 0, stream>>>(x, att, partp);
    emb_reduce <<<(B_ * H_ * M_) / 256, 256, 0, stream>>>(partp, emb);
}

// Round 5
// 176.660 us; speedup vs baseline: 1.4754x; 1.0481x over previous
//
#include <hip/hip_runtime.h>
#include <hip/hip_bf16.h>
#include <stdint.h>

// Problem constants
#define B_ 32
#define N_ 4096
#define M_ 256
#define L_ 128
#define H_ 4
#define BN_ (B_ * N_)          // 131072 flattened rows

typedef __bf16 bf16x8 __attribute__((ext_vector_type(8)));
typedef float  f32x4  __attribute__((ext_vector_type(4)));

__device__ __forceinline__ unsigned short f2bf(float f) {
    // round-to-nearest-even f32 -> bf16
    unsigned int u = __float_as_uint(f);
    u += 0x7fffu + ((u >> 16) & 1u);
    return (unsigned short)(u >> 16);
}
__device__ __forceinline__ unsigned int pack2(float lo, float hi) {
    return (unsigned int)f2bf(lo) | ((unsigned int)f2bf(hi) << 16);
}

// async global->LDS, 16B per lane. LDS dest is wave-uniform base (+lane*16 by HW);
// global src is per-lane.
__device__ __forceinline__ void gload16(const void* g, void* l) {
    __builtin_amdgcn_global_load_lds(
        (const __attribute__((address_space(1))) unsigned int*)g,
        (__attribute__((address_space(3))) unsigned int*)l, 16, 0, 0);
}

// Image geometry: each K-step image is [128 rows][32 k] bf16 = 8192 B,
// row stride 64 B, swizzle byte ^= (row&6)<<3. 16-lane fragment groups read
// 16 distinct rows at fixed 16B col -> 2-way bank aliasing = free (G4, m136);
// measured 0 conflicts in round 4.

// ---------------------------------------------------------------------------
// prep 1: x (BN,256) f32 -> xb images: tile t in [0,1024), step s in [0,8):
// image base = (tile*8 + s)*8192.
// ---------------------------------------------------------------------------
__global__ void prep_x(const float* __restrict__ x, unsigned short* __restrict__ xb) {
    const int blk  = blockIdx.x;        // 4096 = 1024 tiles * 4 ks64
    const int tile = blk >> 2, ks = blk & 3;
    const int i    = threadIdx.x;
    const int kk   = (i & 7) * 8;       // 0..56 within the 64-col chunk
    const int tl   = kk >> 5;           // which 32-k image half
    const int kl   = kk & 31;
    char* dst = (char*)xb + ((size_t)tile * 8 + ks * 2 + tl) * 8192;
#pragma unroll
    for (int rep = 0; rep < 4; ++rep) {
        int row = rep * 32 + (i >> 3);
        const float* gx = x + (size_t)(tile * 128 + row) * M_ + ks * 64 + kk;
        float4 a = *(const float4*)gx;
        float4 b = *(const float4*)(gx + 4);
        uint4 o;
        o.x = pack2(a.x, a.y); o.y = pack2(a.z, a.w);
        o.z = pack2(b.x, b.y); o.w = pack2(b.z, b.w);
        int byte = (row * 64 + kl * 2) ^ ((row & 6) << 3);
        *(uint4*)(dst + byte) = o;
    }
}

// ---------------------------------------------------------------------------
// prep 2: V,U (H,M,L) f32 -> vu images [(h*8 + s)*2 + mat][128 l][32 m] bf16,
// swizzled. Transpose via padded LDS slab (conflict-free).
// ---------------------------------------------------------------------------
__global__ void prep_vu_img(const float* __restrict__ V, const float* __restrict__ U,
                            unsigned short* __restrict__ vu) {
    __shared__ float slab[64][129];     // [m][l], padded
    const int b   = blockIdx.x;         // 32 = h(4) * ks64(4) * mat(2)
    const int mat = b & 1, ks = (b >> 1) & 3, h = b >> 3;
    const float* src = (mat ? U : V) + ((size_t)h * M_ + ks * 64) * L_;
    const int tid = threadIdx.x;
#pragma unroll
    for (int rep = 0; rep < 32; ++rep) {
        int idx = rep * 256 + tid;      // 8192 = 64m x 128l
        slab[idx >> 7][idx & 127] = src[(size_t)(idx >> 7) * L_ + (idx & 127)];
    }
    __syncthreads();
#pragma unroll
    for (int rep = 0; rep < 4; ++rep) {
        int cidx = rep * 256 + tid;     // 1024 chunks of 16B (two 8KB images)
        int l  = cidx >> 3;             // 0..127
        int kk = (cidx & 7) * 8;        // 0..56
        uint4 o;
        o.x = pack2(slab[kk + 0][l], slab[kk + 1][l]);
        o.y = pack2(slab[kk + 2][l], slab[kk + 3][l]);
        o.z = pack2(slab[kk + 4][l], slab[kk + 5][l]);
        o.w = pack2(slab[kk + 6][l], slab[kk + 7][l]);
        int tl = kk >> 5, kl = kk & 31;
        char* dst = (char*)vu + (((size_t)(h * 8 + ks * 2 + tl)) * 2 + mat) * 8192;
        int byte = (l * 64 + kl * 2) ^ ((l & 6) << 3);
        *(uint4*)(dst + byte) = o;
    }
}

// ---------------------------------------------------------------------------
// gemm_fast3: T3+T4 pipelined fused GEMM.
// logits[b,h,n] = sum_l tanh(xV)*sigmoid(xU)*w[h,l]
// 16x16x32 MFMA; block = 128 rows x 128 l x {V,U}, one (tile,h); 4 waves.
// BK=32, 8 fully-unrolled K-steps, 3-buffer LDS (72KB), 2-deep prefetch:
//   iter t: s_waitcnt vmcnt(6) [t's loads done, t+1's in flight];
//           s_barrier; issue stage(t+2); compute(t).
// All LDS offsets / global srcs hoisted (compile-time after unroll).
// Every ds_read is consumed by an MFMA in-step => all LDS reads complete
// before the next barrier => recycling buf (t+2)%3 is race-free.
// ---------------------------------------------------------------------------
__global__ __launch_bounds__(256, 2)
void gemm_fast3(const unsigned short* __restrict__ xb,
                const unsigned short* __restrict__ vu,
                const float* __restrict__ w,
                float* __restrict__ logits) {
    __shared__ __align__(16) unsigned short xs[3][4096];   // 3 x 8KB
    __shared__ __align__(16) unsigned short vs[3][4096];
    __shared__ __align__(16) unsigned short us[3][4096];

    const int orig    = blockIdx.x;                 // 4096, %8==0 -> bijective
    const int logical = (orig & 7) * 512 + (orig >> 3);
    const int tile    = logical >> 2;
    const int h       = logical & 3;

    const int tid  = threadIdx.x;
    const int lane = tid & 63;
    const int wv   = tid >> 6;
    const int g    = lane >> 4;     // k-group 0..3 (k = g*8 + j)
    const int c    = lane & 15;     // row (A) / col (B) within fragment

    f32x4 accV[2][8], accU[2][8];
#pragma unroll
    for (int rf = 0; rf < 2; ++rf)
#pragma unroll
        for (int cf = 0; cf < 8; ++cf) {
            accV[rf][cf] = (f32x4){0.f, 0.f, 0.f, 0.f};
            accU[rf][cf] = (f32x4){0.f, 0.f, 0.f, 0.f};
        }

    const int soff = wv * 2048;     // this wave's quarter of each 8KB image

    // hoisted per-lane global sources (step strides: x 8192 B, v/u 16384 B)
    const char* gxs = (const char*)xb + (size_t)tile * 65536 + soff + lane * 16;
    const char* gvs = (const char*)vu + (size_t)h * 131072 + soff + lane * 16;
    const char* gus = gvs + 8192;

    // hoisted swizzled LDS read byte offsets (within an 8KB image)
    int ar = wv * 32 + c;
    const int aoff0 = (ar * 64 + g * 16) ^ ((ar & 6) << 3);
    const int aoff1 = ((ar + 16) * 64 + g * 16) ^ (((ar + 16) & 6) << 3);
    int boff[8];
#pragma unroll
    for (int cf = 0; cf < 8; ++cf) {
        int l = cf * 16 + c;
        boff[cf] = (l * 64 + g * 16) ^ ((l & 6) << 3);
    }

#define STAGE(t, bufi) do {                                          \
        const char* _gx = gxs + (t) * 8192;                          \
        const char* _gv = gvs + (t) * 16384;                         \
        const char* _gu = gus + (t) * 16384;                         \
        gload16(_gx,        (char*)xs[bufi] + soff);                 \
        gload16(_gx + 1024, (char*)xs[bufi] + soff + 1024);          \
        gload16(_gv,        (char*)vs[bufi] + soff);                 \
        gload16(_gv + 1024, (char*)vs[bufi] + soff + 1024);          \
        gload16(_gu,        (char*)us[bufi] + soff);                 \
        gload16(_gu + 1024, (char*)us[bufi] + soff + 1024);          \
    } while (0)

    // prologue: stage steps 0 and 1 (12 loads in flight)
    STAGE(0, 0);
    STAGE(1, 1);

#pragma unroll
    for (int t = 0; t < 8; ++t) {
        // counted vmcnt: wait only for step t's 6 loads (t+1's stay in flight)
        if (t < 7) asm volatile("s_waitcnt vmcnt(6)" ::: "memory");
        else       asm volatile("s_waitcnt vmcnt(0)" ::: "memory");
        __builtin_amdgcn_s_barrier();
        __builtin_amdgcn_sched_barrier(0);

        if (t < 6) STAGE(t + 2, (t + 2) % 3);   // compile-time buf index

        const int buf = t % 3;                  // compile-time after unroll
        const char* xbuf = (const char*)xs[buf];
        const char* vbuf = (const char*)vs[buf];
        const char* ubuf = (const char*)us[buf];

        bf16x8 a0 = *(const bf16x8*)(xbuf + aoff0);
        bf16x8 a1 = *(const bf16x8*)(xbuf + aoff1);
#pragma unroll
        for (int cf = 0; cf < 8; ++cf) {
            bf16x8 bv = *(const bf16x8*)(vbuf + boff[cf]);
            bf16x8 bu = *(const bf16x8*)(ubuf + boff[cf]);
            accV[0][cf] = __builtin_amdgcn_mfma_f32_16x16x32_bf16(a0, bv, accV[0][cf], 0, 0, 0);
            accV[1][cf] = __builtin_amdgcn_mfma_f32_16x16x32_bf16(a1, bv, accV[1][cf], 0, 0, 0);
            accU[0][cf] = __builtin_amdgcn_mfma_f32_16x16x32_bf16(a0, bu, accU[0][cf], 0, 0, 0);
            accU[1][cf] = __builtin_amdgcn_mfma_f32_16x16x32_bf16(a1, bu, accU[1][cf], 0, 0, 0);
        }
    }
#undef STAGE

    // ---- epilogue: gated = tanh(V)*sigmoid(U), dot w over l, 16-lane reduce ----
    const float* wrow = w + h * L_;
#pragma unroll
    for (int rf = 0; rf < 2; ++rf) {
        float plog[4] = {0.f, 0.f, 0.f, 0.f};
#pragma unroll
        for (int cf = 0; cf < 8; ++cf) {
            float wvv = wrow[cf * 16 + c];
#pragma unroll
            for (int i = 0; i < 4; ++i) {
                float vv = accV[rf][cf][i];
                float uu = accU[rf][cf][i];
                vv = fminf(fmaxf(vv, -20.f), 20.f);
                float A = __expf(2.f * vv);                 // tanh = (A-1)/(A+1)
                float E = __expf(fminf(-uu, 30.f));         // sigmoid = 1/(1+E)
                float gg = __fdividef(A - 1.f, (A + 1.f) * (1.f + E));
                plog[i] += gg * wvv;
            }
        }
#pragma unroll
        for (int i = 0; i < 4; ++i) {
            float v = plog[i];
            v += __shfl_xor(v, 1);
            v += __shfl_xor(v, 2);
            v += __shfl_xor(v, 4);
            v += __shfl_xor(v, 8);      // sum over the 16 col-lanes
            if (c == 0) {
                int rowflat = tile * 128 + wv * 32 + rf * 16 + g * 4 + i;
                int b = rowflat >> 12;           // / N_
                int n = rowflat & (N_ - 1);
                logits[((size_t)b * H_ + h) * N_ + n] = v;
            }
        }
    }
}

// ---------------------------------------------------------------------------
// SLOW PATH (round-1 fallback, used only if ws_size is too small)
// ---------------------------------------------------------------------------
__global__ void prep_vu_slow(const float* __restrict__ V, const float* __restrict__ U,
                             unsigned short* __restrict__ Vt, unsigned short* __restrict__ Ut) {
    int idx = blockIdx.x * 256 + threadIdx.x;
    int m = idx & (M_ - 1);
    int l = (idx >> 8) & (L_ - 1);
    int h = idx >> 15;
    Vt[idx] = f2bf(V[((size_t)h * M_ + m) * L_ + l]);
    Ut[idx] = f2bf(U[((size_t)h * M_ + m) * L_ + l]);
}

#define BM 128
#define BK 64

__global__ __launch_bounds__(256, 2)
void gemm_logits(const float* __restrict__ x,
                 const unsigned short* __restrict__ Vt,
                 const unsigned short* __restrict__ Ut,
                 const float* __restrict__ w,
                 float* __restrict__ logits) {
    __shared__ __align__(16) unsigned short xs[BM * BK];
    __shared__ __align__(16) unsigned short vs[L_ * BK];
    __shared__ __align__(16) unsigned short us[L_ * BK];
    __shared__ float wl[L_];

    const int h    = blockIdx.x >> 10;
    const int tile = blockIdx.x & 1023;
    const int row0 = tile * BM;
    const int tid  = threadIdx.x;
    const int lane = tid & 63;
    const int wave = tid >> 6;

    if (tid < L_) wl[tid] = w[h * L_ + tid];

    f32x4 accV[2][8], accU[2][8];
#pragma unroll
    for (int rf = 0; rf < 2; ++rf)
#pragma unroll
        for (int cf = 0; cf < 8; ++cf) {
            accV[rf][cf] = (f32x4){0.f, 0.f, 0.f, 0.f};
            accU[rf][cf] = (f32x4){0.f, 0.f, 0.f, 0.f};
        }

    const unsigned short* Vh = Vt + (size_t)h * L_ * M_;
    const unsigned short* Uh = Ut + (size_t)h * L_ * M_;
    const int g = lane >> 4;
    const int c = lane & 15;

    for (int ks = 0; ks < 4; ++ks) {
        const int k0 = ks * BK;
        __syncthreads();
#pragma unroll
        for (int p = 0; p < 4; ++p) {
            int row = p * 32 + (tid >> 3);
            int kk  = (tid & 7) * 8;
            const float* gx = x + (size_t)(row0 + row) * M_ + k0 + kk;
            float4 a = *(const float4*)gx;
            float4 b = *(const float4*)(gx + 4);
            uint4 o;
            o.x = pack2(a.x, a.y); o.y = pack2(a.z, a.w);
            o.z = pack2(b.x, b.y); o.w = pack2(b.z, b.w);
            int byte = (row * BK + kk) * 2;
            byte ^= (row & 7) << 4;
            *(uint4*)((char*)xs + byte) = o;
        }
#pragma unroll
        for (int p = 0; p < 4; ++p) {
            int l  = p * 32 + (tid >> 3);
            int kk = (tid & 7) * 8;
            uint4 v = *(const uint4*)(Vh + (size_t)l * M_ + k0 + kk);
            uint4 u = *(const uint4*)(Uh + (size_t)l * M_ + k0 + kk);
            int byte = (l * BK + kk) * 2;
            byte ^= (l & 7) << 4;
            *(uint4*)((char*)vs + byte) = v;
            *(uint4*)((char*)us + byte) = u;
        }
        __syncthreads();
#pragma unroll
        for (int ksub = 0; ksub < 2; ++ksub) {
            bf16x8 afr[2];
#pragma unroll
            for (int rf = 0; rf < 2; ++rf) {
                int row = wave * 32 + rf * 16 + c;
                int byte = (row * BK + ksub * 32 + g * 8) * 2;
                byte ^= (row & 7) << 4;
                afr[rf] = *(const bf16x8*)((const char*)xs + byte);
            }
#pragma unroll
            for (int cf = 0; cf < 8; ++cf) {
                int l = cf * 16 + c;
                int byte = (l * BK + ksub * 32 + g * 8) * 2;
                byte ^= (l & 7) << 4;
                bf16x8 bv = *(const bf16x8*)((const char*)vs + byte);
                bf16x8 bu = *(const bf16x8*)((const char*)us + byte);
#pragma unroll
                for (int rf = 0; rf < 2; ++rf) {
                    accV[rf][cf] = __builtin_amdgcn_mfma_f32_16x16x32_bf16(afr[rf], bv, accV[rf][cf], 0, 0, 0);
                    accU[rf][cf] = __builtin_amdgcn_mfma_f32_16x16x32_bf16(afr[rf], bu, accU[rf][cf], 0, 0, 0);
                }
            }
        }
    }
#pragma unroll
    for (int rf = 0; rf < 2; ++rf) {
        float plog[4] = {0.f, 0.f, 0.f, 0.f};
#pragma unroll
        for (int cf = 0; cf < 8; ++cf) {
            float wvv = wl[cf * 16 + c];
#pragma unroll
            for (int i = 0; i < 4; ++i) {
                float vv = accV[rf][cf][i];
                float uu = accU[rf][cf][i];
                vv = fminf(fmaxf(vv, -20.f), 20.f);
                float e2v = __expf(2.f * vv);
                float t = __fdividef(e2v - 1.f, e2v + 1.f);
                float s = __fdividef(1.f, 1.f + __expf(-uu));
                plog[i] += t * s * wvv;
            }
        }
#pragma unroll
        for (int i = 0; i < 4; ++i) {
            float v = plog[i];
            v += __shfl_xor(v, 1);
            v += __shfl_xor(v, 2);
            v += __shfl_xor(v, 4);
            v += __shfl_xor(v, 8);
            if (c == 0) {
                int rowflat = row0 + wave * 32 + rf * 16 + g * 4 + i;
                int b = rowflat >> 12;
                int n = rowflat & (N_ - 1);
                logits[((size_t)b * H_ + h) * N_ + n] = v;
            }
        }
    }
}

// ---------------------------------------------------------------------------
// softmax^2 (first normalization cancels): a = e^2/sum(e^2), e = m*exp(m*l).
// ---------------------------------------------------------------------------
__global__ __launch_bounds__(256)
void softmax_att(const float* __restrict__ logits, const float* __restrict__ masks,
                 float* __restrict__ att) {
    const int bh = blockIdx.x;
    const int b = bh >> 2, h = bh & 3;
    __shared__ float e2s[N_];
    __shared__ float red[4];
    const int tid = threadIdx.x;

    float sum = 0.f;
#pragma unroll
    for (int i = 0; i < N_ / 256; ++i) {
        int n = i * 256 + tid;
        float lg = logits[((size_t)b * H_ + h) * N_ + n];
        float mv = masks[(size_t)b * N_ + n];
        float e = mv * __expf(mv * lg);
        float e2 = e * e;
        e2s[n] = e2;
        sum += e2;
    }
#pragma unroll
    for (int off = 32; off >= 1; off >>= 1) sum += __shfl_xor(sum, off);
    if ((tid & 63) == 0) red[tid >> 6] = sum;
    __syncthreads();
    float S = red[0] + red[1] + red[2] + red[3];
    float inv = 1.f / S;
#pragma unroll
    for (int i = 0; i < N_ / 256; ++i) {
        int n = i * 256 + tid;
        att[((size_t)h * B_ + b) * N_ + n] = e2s[n] * inv;
    }
}

// ---------------------------------------------------------------------------
// emb: 2-stage deterministic reduction.
// ---------------------------------------------------------------------------
#define NCH 32
#define CHUNK (N_ / NCH)   // 128

__global__ __launch_bounds__(256)
void emb_partial(const float* __restrict__ x, const float* __restrict__ att,
                 float* __restrict__ part) {
    const int bc = blockIdx.x;
    const int b = bc >> 5, ch = bc & 31;
    __shared__ float as[H_][CHUNK];
    const int tid = threadIdx.x;

    for (int i = tid; i < H_ * CHUNK; i += 256) {
        int hh = i >> 7;
        int j  = i & (CHUNK - 1);
        as[hh][j] = att[((size_t)hh * B_ + b) * N_ + ch * CHUNK + j];
    }
    __syncthreads();

    float a0 = 0.f, a1 = 0.f, a2 = 0.f, a3 = 0.f;
    const float* xp = x + ((size_t)b * N_ + ch * CHUNK) * M_ + tid;
#pragma unroll 4
    for (int j = 0; j < CHUNK; ++j) {
        float xv = xp[(size_t)j * M_];
        a0 += as[0][j] * xv;
        a1 += as[1][j] * xv;
        a2 += as[2][j] * xv;
        a3 += as[3][j] * xv;
    }
    float* pp = part + (size_t)bc * H_ * M_ + tid;
    pp[0 * M_] = a0; pp[1 * M_] = a1; pp[2 * M_] = a2; pp[3 * M_] = a3;
}

__global__ __launch_bounds__(256)
void emb_reduce(const float* __restrict__ part, float* __restrict__ emb) {
    int idx = blockIdx.x * 256 + threadIdx.x;
    int b = idx >> 10;
    int r = idx & 1023;
    float s = 0.f;
#pragma unroll
    for (int ci = 0; ci < NCH; ++ci)
        s += part[((size_t)(b * NCH + ci)) * (H_ * M_) + r];
    emb[idx] = s;
}

// ---------------------------------------------------------------------------
extern "C" void kernel_launch(void* const* d_in, const int* in_sizes, int n_in,
                              void* d_out, int out_size, void* d_ws, size_t ws_size,
                              hipStream_t stream) {
    const float* x     = (const float*)d_in[0];
    const float* masks = (const float*)d_in[1];
    const float* V     = (const float*)d_in[2];
    const float* U     = (const float*)d_in[3];
    const float* w     = (const float*)d_in[4];

    float* att = (float*)d_out;                       // (H,B,N,1)
    float* emb = att + (size_t)H_ * B_ * N_;          // (B,H*M)

    char* ws = (char*)d_ws;
    const size_t XB_BYTES  = (size_t)1024 * 8 * 8192;         // 67,108,864
    const size_t VU_BYTES  = (size_t)64 * 8192;               // 524,288
    const size_t LG_BYTES  = (size_t)B_ * H_ * N_ * 4;        // 2,097,152
    const size_t PT_BYTES  = (size_t)B_ * NCH * H_ * M_ * 4;  // 4,194,304
    const size_t NEED_FAST = XB_BYTES + VU_BYTES + LG_BYTES + PT_BYTES;

    float* logits;
    float* partp;

    if (ws_size >= NEED_FAST) {
        unsigned short* xb = (unsigned short*)ws;
        unsigned short* vu = (unsigned short*)(ws + XB_BYTES);
        logits = (float*)(ws + XB_BYTES + VU_BYTES);
        partp  = (float*)(ws + XB_BYTES + VU_BYTES + LG_BYTES);

        prep_x     <<<4096, 256, 0, stream>>>(x, xb);
        prep_vu_img<<<32,   256, 0, stream>>>(V, U, vu);
        gemm_fast3 <<<4096, 256, 0, stream>>>(xb, vu, w, logits);
    } else {
        unsigned short* Vt = (unsigned short*)ws;
        unsigned short* Ut = (unsigned short*)(ws + 262144);
        logits = (float*)(ws + 524288);
        partp  = (float*)(ws + 524288 + LG_BYTES);

        prep_vu_slow<<<512, 256, 0, stream>>>(V, U, Vt, Ut);
        gemm_logits <<<4096, 256, 0, stream>>>(x, Vt, Ut, w, logits);
    }

    softmax_att<<<B_ * H_,              256, 0, stream>>>(logits, masks, att);
    emb_partial<<<B_ * NCH,             256, 0, stream>>>(x, att, partp);
    emb_reduce <<<(B_ * H_ * M_) / 256, 256, 0, stream>>>(partp, emb);
}